// Round 11
// baseline (2329.053 us; speedup 1.0000x reference)
//
#include <hip/hip_runtime.h>

typedef _Float16 h8 __attribute__((ext_vector_type(8)));
typedef float f32x4 __attribute__((ext_vector_type(4)));
typedef int  i4 __attribute__((ext_vector_type(4)));

#define NTHREADS 1024
#define ROWS 16
#define NBLK 256   // 4096 tokens / 16 rows

// LDS layout (bytes):
//   buf8A : 16x1024 int8 swizzled  at      0  (16384)  L0 out -> L1 in   (aliased: L3 reduce)
//   buf8B : 16x1024 int8 swizzled  at  16384  (16384)  L1 out -> L2 in   (aliased: Yf init)
//   buf8C : 16x1024 int8 swizzled  at  32768  (16384)  L2 out -> L3 in
//   Yh    : 16x128  fp16 swizzled  at  49152  ( 4096)
#define SMEM_BYTES 53248

__device__ __forceinline__ float fast_tanh(float x) {
    float e = __expf(2.0f * x);
    return 1.0f - 2.0f / (e + 1.0f);
}

// ---------------- weight pack kernels ----------------
// fp16 pack (W0): fragment idx = ((w*NK + kk)*4 + ct)*64 + lane, 16B (h8) each
//   holds W[w*64 + ct*16 + (lane&15)][kk*32 + (lane>>4)*8 + j], j=0..7
template<int K>
__global__ void __launch_bounds__(256) pack_kernel(const float* __restrict__ src,
                                                   _Float16* __restrict__ dst, int nfrag) {
    constexpr int NK = K / 32;
    int idx = blockIdx.x * 256 + threadIdx.x;
    if (idx >= nfrag) return;
    int lane = idx & 63;
    int ct   = (idx >> 6) & 3;
    int kk   = (idx >> 8) % NK;
    int w    = idx / (256 * NK);
    int col  = w * 64 + ct * 16 + (lane & 15);
    int kb   = kk * 32 + (lane >> 4) * 8;
    const float* s = src + (size_t)col * K + kb;
    f32x4 v0 = *(const f32x4*)s;
    f32x4 v1 = *(const f32x4*)(s + 4);
    h8 h;
    h[0]=(_Float16)v0[0]; h[1]=(_Float16)v0[1]; h[2]=(_Float16)v0[2]; h[3]=(_Float16)v0[3];
    h[4]=(_Float16)v1[0]; h[5]=(_Float16)v1[1]; h[6]=(_Float16)v1[2]; h[7]=(_Float16)v1[3];
    *(h8*)(dst + (size_t)idx * 8) = h;
}

// int8 pack (W1/W2, K=1024): fragment idx = ((w*16 + kk)*4 + ct)*64 + lane, 16B each
//   holds round(W[w*64 + ct*16 + (lane&15)][kk*64 + (lane>>4)*16 + j] * 32*127), j=0..15
__global__ void __launch_bounds__(256) pack8_kernel(const float* __restrict__ src,
                                                    char* __restrict__ dst, int nfrag) {
    int idx = blockIdx.x * 256 + threadIdx.x;
    if (idx >= nfrag) return;
    int lane = idx & 63;
    int ct   = (idx >> 6) & 3;
    int kk   = (idx >> 8) & 15;
    int w    = idx >> 12;
    int col  = w * 64 + ct * 16 + (lane & 15);
    int kb   = kk * 64 + (lane >> 4) * 16;
    const float* s = src + (size_t)col * 1024 + kb;
    union { char q[16]; i4 v; } u;
#pragma unroll
    for (int j = 0; j < 16; ++j)
        u.q[j] = (char)__float2int_rn(s[j] * 4064.0f);   // 32*127
    *(i4*)(dst + (size_t)idx * 16) = u.v;
}

// int8 W3 pack (128 cols, K=1024): fragment idx = (cg*16 + kk)*64 + lane, 16B each
//   holds round(W3[cg*16 + (lane&15)][kk*64 + (lane>>4)*16 + j] * 4064), j=0..15
__global__ void __launch_bounds__(256) pack3q_kernel(const float* __restrict__ src,
                                                     char* __restrict__ dst, int nfrag) {
    int idx = blockIdx.x * 256 + threadIdx.x;
    if (idx >= nfrag) return;
    int lane = idx & 63;
    int kk   = (idx >> 6) & 15;
    int cg   = idx >> 10;
    int col  = cg * 16 + (lane & 15);
    int kb   = kk * 64 + (lane >> 4) * 16;
    const float* s = src + (size_t)col * 1024 + kb;
    union { char q[16]; i4 v; } u;
#pragma unroll
    for (int j = 0; j < 16; ++j)
        u.q[j] = (char)__float2int_rn(s[j] * 4064.0f);
    *(i4*)(dst + (size_t)idx * 16) = u.v;
}

// ---------------- layer 0: fp16 x fp16 (K=128) -> int8 out ----------------
__device__ __forceinline__ void mlp0(const char* __restrict__ src, char* __restrict__ dst,
                                     const _Float16* __restrict__ Wp,
                                     const float* __restrict__ bias,
                                     int w, int l15, int lhi, int lane)
{
    constexpr int NK = 4;
    const int colbase = w * 64;
    const _Float16* wb = Wp + (size_t)w * NK * 2048 + lane * 8;

    f32x4 acc[4];
#pragma unroll
    for (int ct = 0; ct < 4; ++ct) {
        float bv = bias[colbase + ct * 16 + l15];
        f32x4 a; a[0] = bv; a[1] = bv; a[2] = bv; a[3] = bv;
        acc[ct] = a;
    }

    h8 bE[4], bO[4], aE, aO;
    auto loadB = [&](h8* b, int kk) {
#pragma unroll
        for (int ct = 0; ct < 4; ++ct)
            b[ct] = *(const h8*)(wb + (size_t)kk * 2048 + ct * 512);
    };
    auto loadA = [&](h8& a, int kk) {
        int byte = (l15 * 256 + kk * 64 + lhi * 16) ^ ((l15 & 7) << 4);
        a = *(const h8*)(src + byte);
    };
    auto mfma4 = [&](h8& a, h8* b) {
        __builtin_amdgcn_s_setprio(1);
#pragma unroll
        for (int ct = 0; ct < 4; ++ct)
            acc[ct] = __builtin_amdgcn_mfma_f32_16x16x32_f16(a, b[ct], acc[ct], 0, 0, 0);
        __builtin_amdgcn_s_setprio(0);
    };

    loadB(bE, 0); loadA(aE, 0);
    loadB(bO, 1); loadA(aO, 1);
    mfma4(aE, bE);
    loadB(bE, 2); loadA(aE, 2);
    mfma4(aO, bO);
    loadB(bO, 3); loadA(aO, 3);
    mfma4(aE, bE);
    mfma4(aO, bO);

#pragma unroll
    for (int ct = 0; ct < 4; ++ct)
#pragma unroll
        for (int j = 0; j < 4; ++j) {
            int row = lhi * 4 + j;
            int gc = colbase + ct * 16 + l15;
            int q = __float2int_rn(fast_tanh(acc[ct][j]) * 127.0f);
            int byte = (row * 1024 + gc) ^ ((row & 7) << 4);
            *(char*)(dst + byte) = (char)q;
        }
}

// ------- layers 1/2: int8 x int8, 4-set rotation (depth-3 prefetch, ~16 loads in flight) -------
__device__ __forceinline__ void mlp8(const char* __restrict__ src, char* __restrict__ dst,
                                     const char* __restrict__ Wq,
                                     const float* __restrict__ bias,
                                     int w, int l15, int lhi, int lane)
{
    const int colbase = w * 64;
    const char* wb = Wq + (size_t)w * 65536 + lane * 16;

    i4 acc[4];
#pragma unroll
    for (int ct = 0; ct < 4; ++ct) { i4 z; z[0]=0; z[1]=0; z[2]=0; z[3]=0; acc[ct] = z; }

    i4 S0[4], S1[4], S2[4], S3[4];
    i4 A0, A1, A2, A3;

    auto loadB = [&](i4* b, int kk) {
#pragma unroll
        for (int ct = 0; ct < 4; ++ct)
            b[ct] = *(const i4*)(wb + (size_t)(kk * 4 + ct) * 1024);
    };
    auto loadA = [&](i4& a, int kk) {
        int byte = (l15 * 1024 + kk * 64 + lhi * 16) ^ ((l15 & 7) << 4);
        a = *(const i4*)(src + byte);
    };
    auto mfma4 = [&](i4& a, i4* b) {
        __builtin_amdgcn_s_setprio(1);
#pragma unroll
        for (int ct = 0; ct < 4; ++ct)
            acc[ct] = __builtin_amdgcn_mfma_i32_16x16x64_i8(a, b[ct], acc[ct], 0, 0, 0);
        __builtin_amdgcn_s_setprio(0);
    };

    loadB(S0, 0); loadB(S1, 1); loadA(A0, 0); loadA(A1, 1);
    __builtin_amdgcn_sched_barrier(0);
#pragma unroll 1
    for (int base = 0; base < 16; base += 4) {
        loadB(S2, base + 2); loadB(S3, base + 3); loadA(A2, base + 2); loadA(A3, base + 3);
        __builtin_amdgcn_sched_barrier(0);
        mfma4(A0, S0); mfma4(A1, S1);
        if (base + 4 < 16) {
            loadB(S0, base + 4); loadB(S1, base + 5); loadA(A0, base + 4); loadA(A1, base + 5);
        }
        __builtin_amdgcn_sched_barrier(0);
        mfma4(A2, S2); mfma4(A3, S3);
        __builtin_amdgcn_sched_barrier(0);
    }

    const float DEQ = 1.0f / 516128.0f;   // 1/(32*127*127)
#pragma unroll
    for (int ct = 0; ct < 4; ++ct) {
        int gc = colbase + ct * 16 + l15;
        float bv = bias[gc];
#pragma unroll
        for (int j = 0; j < 4; ++j) {
            int row = lhi * 4 + j;
            float v = fast_tanh((float)acc[ct][j] * DEQ + bv);
            int q = __float2int_rn(v * 127.0f);
            int byte = (row * 1024 + gc) ^ ((row & 7) << 4);
            *(char*)(dst + byte) = (char)q;
        }
    }
}

__global__ void
__attribute__((amdgpu_flat_work_group_size(NTHREADS, NTHREADS)))
node_kernel(const float* __restrict__ y0,
            const float* __restrict__ tarr,
            const float* __restrict__ W_aug,
            const float* __restrict__ b_aug,
            const float* __restrict__ b0,
            const float* __restrict__ b1,
            const float* __restrict__ b2,
            const float* __restrict__ b3,
            const _Float16* __restrict__ W0p,
            const char* __restrict__ W1q,
            const char* __restrict__ W2q,
            const char* __restrict__ W3q,
            float* __restrict__ out)
{
    __shared__ __align__(16) char smem[SMEM_BYTES];
    char* buf8A = smem;
    char* buf8B = smem + 16384;
    char* buf8C = smem + 32768;
    i4*   red   = (i4*)smem;               // aliases buf8A (free during L3)
    float* Yf   = (float*)(smem + 16384);  // aliases buf8B (init only)
    char* Yh    = smem + 49152;

    const int tid  = threadIdx.x;
    const int lane = tid & 63;
    const int w    = tid >> 6;       // 0..15
    const int l15  = lane & 15;
    const int lhi  = lane >> 4;
    const int row0 = blockIdx.x * ROWS;

    const float dtv = tarr[1] - tarr[0];

    // ---- load y0 rows into Yf[:, 0:64] ----
    if (tid < 256) {
        int idx = tid * 4;
        int r = idx >> 6;
        int c = idx & 63;
        f32x4 v = *(const f32x4*)(y0 + (size_t)(row0 + r) * 64 + c);
        *(f32x4*)(Yf + r * 128 + c) = v;
    }
    __syncthreads();

    // ---- augment: Yf[:, 64:128] = y0_row @ W_aug^T + b_aug (1 elem/thread) ----
    {
        int r = tid >> 6;
        int a0 = tid & 63;
        float acc = b_aug[a0];
        for (int d = 0; d < 64; ++d)
            acc += Yf[r * 128 + d] * W_aug[a0 * 64 + d];
        Yf[r * 128 + 64 + a0] = acc;
    }
    __syncthreads();

    // ---- initial fp16 mirror of Y (swizzled) ----
    if (tid < 256) {
        int r = tid >> 4;
        int c = (tid & 15) * 8;
        const float* p = Yf + r * 128 + c;
        h8 h;
#pragma unroll
        for (int j = 0; j < 8; ++j) h[j] = (_Float16)p[j];
        int byte = ((r * 128 + c) * 2) ^ ((r & 7) << 4);
        *(h8*)(Yh + byte) = h;
    }
    // thread-owned state (waves 0..7): col g = w*16+l15, rows lhi*4+j
    const int g = w * 16 + l15;
    f32x4 yreg;
    if (w < 8) {
#pragma unroll
        for (int j = 0; j < 4; ++j)
            yreg[j] = Yf[(lhi * 4 + j) * 128 + g];
    }
    __syncthreads();

    // layer-3: all 16 waves. cg = w&7 (16 cols), kk half = (w>>3)*8
    const int cg  = w & 7;
    const int kk0 = (w >> 3) * 8;
    const char* wb3 = W3q + (size_t)cg * 16384 + lane * 16;
    const float b3v = (w < 8) ? b3[g] : 0.0f;
    const float DEQ3 = 1.0f / 516128.0f;

    // ---- 31 Euler steps ----
    for (int s = 0; s < 31; ++s) {
        mlp0(Yh, buf8A, W0p, b0, w, l15, lhi, lane);
        __syncthreads();
        mlp8(buf8A, buf8B, W1q, b1, w, l15, lhi, lane);
        __syncthreads();
        mlp8(buf8B, buf8C, W2q, b2, w, l15, lhi, lane);
        __syncthreads();

        // layer 3: DY[16][128] = buf8C @ W3q^T + b3 (int8, K split across wave halves)
        {
            i4 acc3; acc3[0]=0; acc3[1]=0; acc3[2]=0; acc3[3]=0;

            i4 c3E, c3O, x3E, x3O;
            auto loadB3 = [&](i4& b, int kk) {
                b = *(const i4*)(wb3 + (size_t)kk * 1024);
            };
            auto loadA3 = [&](i4& a, int kk) {
                int byte = (l15 * 1024 + kk * 64 + lhi * 16) ^ ((l15 & 7) << 4);
                a = *(const i4*)(buf8C + byte);
            };

            loadB3(c3E, kk0 + 0); loadA3(x3E, kk0 + 0);
#pragma unroll
            for (int p = 0; p < 3; ++p) {
                loadB3(c3O, kk0 + 2 * p + 1); loadA3(x3O, kk0 + 2 * p + 1);
                acc3 = __builtin_amdgcn_mfma_i32_16x16x64_i8(x3E, c3E, acc3, 0, 0, 0);
                loadB3(c3E, kk0 + 2 * p + 2); loadA3(x3E, kk0 + 2 * p + 2);
                acc3 = __builtin_amdgcn_mfma_i32_16x16x64_i8(x3O, c3O, acc3, 0, 0, 0);
            }
            loadB3(c3O, kk0 + 7); loadA3(x3O, kk0 + 7);
            acc3 = __builtin_amdgcn_mfma_i32_16x16x64_i8(x3E, c3E, acc3, 0, 0, 0);
            acc3 = __builtin_amdgcn_mfma_i32_16x16x64_i8(x3O, c3O, acc3, 0, 0, 0);

            // waves 8..15 publish int partials into red (aliases buf8A, free here)
            if (w >= 8)
                red[cg * 64 + lane] = acc3;
            __syncthreads();
            if (w < 8) {
                i4 part = red[w * 64 + lane];
#pragma unroll
                for (int j = 0; j < 4; ++j) {
                    int row = lhi * 4 + j;
                    float dy = (float)(acc3[j] + part[j]) * DEQ3 + b3v;
                    float nv = yreg[j] + dtv * dy;
                    yreg[j] = nv;
                    int byte = ((row * 128 + g) * 2) ^ ((row & 7) << 4);
                    *(_Float16*)(Yh + byte) = (_Float16)nv;
                }
            }
        }
        __syncthreads();
    }

    // ---- output: out[token][0:64] from registers (cols 0..63 = waves 0..3) ----
    if (w < 4) {
#pragma unroll
        for (int j = 0; j < 4; ++j) {
            int row = lhi * 4 + j;
            out[(size_t)(row0 + row) * 64 + g] = yreg[j];
        }
    }
}

extern "C" void kernel_launch(void* const* d_in, const int* in_sizes, int n_in,
                              void* d_out, int out_size, void* d_ws, size_t ws_size,
                              hipStream_t stream)
{
    const float* y0    = (const float*)d_in[0];
    const float* tarr  = (const float*)d_in[1];
    const float* W_aug = (const float*)d_in[2];
    const float* b_aug = (const float*)d_in[3];
    const float* W0    = (const float*)d_in[4];
    const float* b0    = (const float*)d_in[5];
    const float* W1    = (const float*)d_in[6];
    const float* b1    = (const float*)d_in[7];
    const float* W2    = (const float*)d_in[8];
    const float* b2    = (const float*)d_in[9];
    const float* W3    = (const float*)d_in[10];
    const float* b3    = (const float*)d_in[11];

    // d_ws layout (bytes): W0p fp16 @0 (262144), W1q @262144 (1048576),
    //                      W2q @1310720 (1048576), W3q @2359296 (131072)
    _Float16* W0p = (_Float16*)d_ws;
    char* W1q = (char*)d_ws + 262144;
    char* W2q = (char*)d_ws + 1310720;
    char* W3q = (char*)d_ws + 2359296;

    pack_kernel<128><<<16384 / 256, 256, 0, stream>>>(W0, W0p, 16384);
    pack8_kernel<<<65536 / 256, 256, 0, stream>>>(W1, W1q, 65536);
    pack8_kernel<<<65536 / 256, 256, 0, stream>>>(W2, W2q, 65536);
    pack3q_kernel<<<8192 / 256, 256, 0, stream>>>(W3, W3q, 8192);

    node_kernel<<<NBLK, NTHREADS, 0, stream>>>(y0, tarr, W_aug, b_aug,
                                               b0, b1, b2, b3,
                                               W0p, W1q, W2q, W3q,
                                               (float*)d_out);
}

// Round 12
// 1281.367 us; speedup vs baseline: 1.8176x; 1.8176x over previous
//
#include <hip/hip_runtime.h>

typedef _Float16 h8 __attribute__((ext_vector_type(8)));
typedef float f32x4 __attribute__((ext_vector_type(4)));
typedef int  i4 __attribute__((ext_vector_type(4)));

#define NTHREADS 1024
#define ROWS 16
#define NBLK 256   // 4096 tokens / 16 rows

// LDS layout (bytes), total = 160 KiB exactly:
//   buf8A : 16x1024 int8 swizzled @      0 (16384)  L0out->L1in, L2out->L3in; init: Yf f32
//   buf8B : 16x1024 int8 swizzled @  16384 (16384)  L1out->L2in
//           Yh fp16 16x128 swz    @  16384 ( 4096)  (alias; dead while buf8B live)
//           red i4[512]           @  24576 ( 8192)  (alias; L3 reduce scratch)
//   ring  : 16 waves x 2 slots x 4096 @ 32768 (131072)  async W-panel staging
#define SMEM_BYTES 163840

#define GLOAD16(gp, lp) __builtin_amdgcn_global_load_lds( \
    (const __attribute__((address_space(1))) void*)(gp),  \
    (__attribute__((address_space(3))) void*)(lp), 16, 0, 0)

__device__ __forceinline__ float fast_tanh(float x) {
    float e = __expf(2.0f * x);
    return 1.0f - 2.0f / (e + 1.0f);
}

// light barrier: flush LDS writes + block barrier WITHOUT draining vmcnt
// (keeps our async global_load_lds prefetch alive across the barrier)
__device__ __forceinline__ void lightbar() {
    asm volatile("s_waitcnt lgkmcnt(0)" ::: "memory");
    __builtin_amdgcn_sched_barrier(0);
    __builtin_amdgcn_s_barrier();
    __builtin_amdgcn_sched_barrier(0);
}

// ---------------- weight pack kernels (unchanged layouts) ----------------
template<int K>
__global__ void __launch_bounds__(256) pack_kernel(const float* __restrict__ src,
                                                   _Float16* __restrict__ dst, int nfrag) {
    constexpr int NK = K / 32;
    int idx = blockIdx.x * 256 + threadIdx.x;
    if (idx >= nfrag) return;
    int lane = idx & 63;
    int ct   = (idx >> 6) & 3;
    int kk   = (idx >> 8) % NK;
    int w    = idx / (256 * NK);
    int col  = w * 64 + ct * 16 + (lane & 15);
    int kb   = kk * 32 + (lane >> 4) * 8;
    const float* s = src + (size_t)col * K + kb;
    f32x4 v0 = *(const f32x4*)s;
    f32x4 v1 = *(const f32x4*)(s + 4);
    h8 h;
    h[0]=(_Float16)v0[0]; h[1]=(_Float16)v0[1]; h[2]=(_Float16)v0[2]; h[3]=(_Float16)v0[3];
    h[4]=(_Float16)v1[0]; h[5]=(_Float16)v1[1]; h[6]=(_Float16)v1[2]; h[7]=(_Float16)v1[3];
    *(h8*)(dst + (size_t)idx * 8) = h;
}

__global__ void __launch_bounds__(256) pack8_kernel(const float* __restrict__ src,
                                                    char* __restrict__ dst, int nfrag) {
    int idx = blockIdx.x * 256 + threadIdx.x;
    if (idx >= nfrag) return;
    int lane = idx & 63;
    int ct   = (idx >> 6) & 3;
    int kk   = (idx >> 8) & 15;
    int w    = idx >> 12;
    int col  = w * 64 + ct * 16 + (lane & 15);
    int kb   = kk * 64 + (lane >> 4) * 16;
    const float* s = src + (size_t)col * 1024 + kb;
    union { char q[16]; i4 v; } u;
#pragma unroll
    for (int j = 0; j < 16; ++j)
        u.q[j] = (char)__float2int_rn(s[j] * 4064.0f);   // 32*127
    *(i4*)(dst + (size_t)idx * 16) = u.v;
}

__global__ void __launch_bounds__(256) pack3q_kernel(const float* __restrict__ src,
                                                     char* __restrict__ dst, int nfrag) {
    int idx = blockIdx.x * 256 + threadIdx.x;
    if (idx >= nfrag) return;
    int lane = idx & 63;
    int kk   = (idx >> 6) & 15;
    int cg   = idx >> 10;
    int col  = cg * 16 + (lane & 15);
    int kb   = kk * 64 + (lane >> 4) * 16;
    const float* s = src + (size_t)col * 1024 + kb;
    union { char q[16]; i4 v; } u;
#pragma unroll
    for (int j = 0; j < 16; ++j)
        u.q[j] = (char)__float2int_rn(s[j] * 4064.0f);
    *(i4*)(dst + (size_t)idx * 16) = u.v;
}

// ---------------- layer 0: fp16 x fp16 (K=128), reg ping-pong (R10 proven) ----------------
__device__ __forceinline__ void mlp0(const char* __restrict__ src, char* __restrict__ dst,
                                     const _Float16* __restrict__ Wp, f32x4 bv,
                                     int w, int l15, int lhi, int lane)
{
    constexpr int NK = 4;
    const int colbase = w * 64;
    const _Float16* wb = Wp + (size_t)w * NK * 2048 + lane * 8;

    f32x4 acc[4];
#pragma unroll
    for (int ct = 0; ct < 4; ++ct) {
        f32x4 a; a[0] = bv[ct]; a[1] = bv[ct]; a[2] = bv[ct]; a[3] = bv[ct];
        acc[ct] = a;
    }

    h8 bE[4], bO[4], aE, aO;
    auto loadB = [&](h8* b, int kk) {
#pragma unroll
        for (int ct = 0; ct < 4; ++ct)
            b[ct] = *(const h8*)(wb + (size_t)kk * 2048 + ct * 512);
    };
    auto loadA = [&](h8& a, int kk) {
        int byte = (l15 * 256 + kk * 64 + lhi * 16) ^ ((l15 & 7) << 4);
        a = *(const h8*)(src + byte);
    };
    auto mfma4 = [&](h8& a, h8* b) {
        __builtin_amdgcn_s_setprio(1);
#pragma unroll
        for (int ct = 0; ct < 4; ++ct)
            acc[ct] = __builtin_amdgcn_mfma_f32_16x16x32_f16(a, b[ct], acc[ct], 0, 0, 0);
        __builtin_amdgcn_s_setprio(0);
    };

    loadB(bE, 0); loadA(aE, 0);
    loadB(bO, 1); loadA(aO, 1);
    mfma4(aE, bE);
    loadB(bE, 2); loadA(aE, 2);
    mfma4(aO, bO);
    loadB(bO, 3); loadA(aO, 3);
    mfma4(aE, bE);
    mfma4(aO, bO);

#pragma unroll
    for (int ct = 0; ct < 4; ++ct)
#pragma unroll
        for (int j = 0; j < 4; ++j) {
            int row = lhi * 4 + j;
            int gc = colbase + ct * 16 + l15;
            int q = __float2int_rn(fast_tanh(acc[ct][j]) * 127.0f);
            int byte = (row * 1024 + gc) ^ ((row & 7) << 4);
            *(char*)(dst + byte) = (char)q;
        }
}

// ---- async staging: issue chunks c0, c0+1 (4 x 16B gload_lds each) into wave-private ring ----
__device__ __forceinline__ void stage2(const char* wbl /* W + w*65536 + lane*16 */,
                                       char* ringW /* uniform wave slot base */, int c0)
{
#pragma unroll
    for (int c = 0; c < 2; ++c) {
        const char* g = wbl + (size_t)(c0 + c) * 4096;
        char* l = ringW + ((c0 + c) & 1) * 4096;
#pragma unroll
        for (int ct = 0; ct < 4; ++ct)
            GLOAD16(g + ct * 1024, l + ct * 1024);
    }
}

// ------- layers 1/2 compute: int8, B from LDS ring (vmcnt-counted pipeline) -------
__device__ __forceinline__ void mlp8c(const char* __restrict__ src, char* __restrict__ dst,
                                      const char* wbl, char* ringW, const char* ringR,
                                      f32x4 bv, int w, int l15, int lhi)
{
    const int colbase = w * 64;
    i4 acc[4];
#pragma unroll
    for (int ct = 0; ct < 4; ++ct) { i4 z; z[0]=0; z[1]=0; z[2]=0; z[3]=0; acc[ct] = z; }

    i4 B0, B1, B2, B3, A;
    auto readSlot = [&](int kk) {
        const char* sl = ringR + (kk & 1) * 4096;
        B0 = *(const i4*)(sl);
        B1 = *(const i4*)(sl + 1024);
        B2 = *(const i4*)(sl + 2048);
        B3 = *(const i4*)(sl + 3072);
        int byte = (l15 * 1024 + kk * 64 + lhi * 16) ^ ((l15 & 7) << 4);
        A = *(const i4*)(src + byte);
    };
    auto mfma4 = [&]() {
        __builtin_amdgcn_s_setprio(1);
        acc[0] = __builtin_amdgcn_mfma_i32_16x16x64_i8(A, B0, acc[0], 0, 0, 0);
        acc[1] = __builtin_amdgcn_mfma_i32_16x16x64_i8(A, B1, acc[1], 0, 0, 0);
        acc[2] = __builtin_amdgcn_mfma_i32_16x16x64_i8(A, B2, acc[2], 0, 0, 0);
        acc[3] = __builtin_amdgcn_mfma_i32_16x16x64_i8(A, B3, acc[3], 0, 0, 0);
        __builtin_amdgcn_s_setprio(0);
    };

    // entry state: chunks 0,1 issued by stage2 prologue (8 outstanding)
#pragma unroll 1
    for (int kk = 0; kk < 15; ++kk) {
        asm volatile("s_waitcnt vmcnt(4)" ::: "memory");   // chunk kk landed
        __builtin_amdgcn_sched_barrier(0);
        readSlot(kk);
        asm volatile("s_waitcnt lgkmcnt(0)" ::: "memory"); // reads done before slot reuse
        __builtin_amdgcn_sched_barrier(0);
        if (kk < 14) {                                     // issue chunk kk+2 into slot kk&1
            const char* g = wbl + (size_t)(kk + 2) * 4096;
            char* l = ringW + (kk & 1) * 4096;
#pragma unroll
            for (int ct = 0; ct < 4; ++ct)
                GLOAD16(g + ct * 1024, l + ct * 1024);
        }
        __builtin_amdgcn_sched_barrier(0);
        mfma4();
    }
    asm volatile("s_waitcnt vmcnt(0)" ::: "memory");       // chunk 15 landed
    __builtin_amdgcn_sched_barrier(0);
    readSlot(15);
    asm volatile("s_waitcnt lgkmcnt(0)" ::: "memory");
    __builtin_amdgcn_sched_barrier(0);
    mfma4();

    const float DEQ = 1.0f / 516128.0f;   // 1/(32*127*127)
#pragma unroll
    for (int ct = 0; ct < 4; ++ct) {
        int gc = colbase + ct * 16 + l15;
#pragma unroll
        for (int j = 0; j < 4; ++j) {
            int row = lhi * 4 + j;
            float v = fast_tanh((float)acc[ct][j] * DEQ + bv[ct]);
            int q = __float2int_rn(v * 127.0f);
            int byte = (row * 1024 + gc) ^ ((row & 7) << 4);
            *(char*)(dst + byte) = (char)q;
        }
    }
}

__global__ void
__attribute__((amdgpu_flat_work_group_size(NTHREADS, NTHREADS)))
node_kernel(const float* __restrict__ y0,
            const float* __restrict__ tarr,
            const float* __restrict__ W_aug,
            const float* __restrict__ b_aug,
            const float* __restrict__ b0,
            const float* __restrict__ b1,
            const float* __restrict__ b2,
            const float* __restrict__ b3,
            const _Float16* __restrict__ W0p,
            const char* __restrict__ W1q,
            const char* __restrict__ W2q,
            const char* __restrict__ W3q,
            float* __restrict__ out)
{
    __shared__ __align__(16) char smem[SMEM_BYTES];
    char* buf8A = smem;
    char* buf8B = smem + 16384;
    char* Yh    = smem + 16384;            // alias buf8B[0:4096]
    i4*   red   = (i4*)(smem + 24576);     // alias buf8B[8192:16384]
    float* Yf   = (float*)smem;            // alias buf8A (init only)
    char* ring  = smem + 32768;

    const int tid  = threadIdx.x;
    const int lane = tid & 63;
    const int w    = tid >> 6;       // 0..15
    const int l15  = lane & 15;
    const int lhi  = lane >> 4;
    const int row0 = blockIdx.x * ROWS;

    const float dtv = tarr[1] - tarr[0];

    // ---- load y0 rows into Yf[:, 0:64] ----
    if (tid < 256) {
        int idx = tid * 4;
        int r = idx >> 6;
        int c = idx & 63;
        f32x4 v = *(const f32x4*)(y0 + (size_t)(row0 + r) * 64 + c);
        *(f32x4*)(Yf + r * 128 + c) = v;
    }
    __syncthreads();

    // ---- augment: Yf[:, 64:128] = y0_row @ W_aug^T + b_aug (1 elem/thread) ----
    {
        int r = tid >> 6;
        int a0 = tid & 63;
        float acc = b_aug[a0];
        for (int d = 0; d < 64; ++d)
            acc += Yf[r * 128 + d] * W_aug[a0 * 64 + d];
        __syncthreads();               // all reads of Yf row halves done before write
        Yf[r * 128 + 64 + a0] = acc;
    }
    __syncthreads();

    // thread-owned state (waves 0..7): col g = w*16+l15, rows lhi*4+j
    const int g = w * 16 + l15;
    f32x4 yreg;
    if (w < 8) {
#pragma unroll
        for (int j = 0; j < 4; ++j)
            yreg[j] = Yf[(lhi * 4 + j) * 128 + g];
    }
    // initial fp16 mirror of Y (swizzled) -- build into registers first, then store
    h8 yh0;
    int yh0_byte;
    if (tid < 256) {
        int r = tid >> 4;
        int c = (tid & 15) * 8;
        const float* p = Yf + r * 128 + c;
#pragma unroll
        for (int j = 0; j < 8; ++j) yh0[j] = (_Float16)p[j];
        yh0_byte = ((r * 128 + c) * 2) ^ ((r & 7) << 4);
    }
    __syncthreads();                   // Yf fully read before Yh (aliases nothing of Yf; buf8B) write
    if (tid < 256) *(h8*)(Yh + yh0_byte) = yh0;
    __syncthreads();

    // per-wave pointers
    const _Float16* Wb0 = W0p;                                   // used inside mlp0
    const char* wb1 = W1q + (size_t)w * 65536 + lane * 16;
    const char* wb2 = W2q + (size_t)w * 65536 + lane * 16;
    char* ringW = ring + w * 8192;           // wave-uniform
    const char* ringR = ringW + lane * 16;   // per-lane read base

    // preload biases into registers (keep vmcnt clean inside mlp8c)
    f32x4 b0v, b1v, b2v;
#pragma unroll
    for (int ct = 0; ct < 4; ++ct) {
        b0v[ct] = b0[w * 64 + ct * 16 + l15];
        b1v[ct] = b1[w * 64 + ct * 16 + l15];
        b2v[ct] = b2[w * 64 + ct * 16 + l15];
    }
    const int cg  = w & 7;
    const int kk0 = (w >> 3) * 8;
    const char* wb3 = W3q + (size_t)cg * 16384 + lane * 16;
    const float b3v = (w < 8) ? b3[g] : 0.0f;
    const float DEQ3 = 1.0f / 516128.0f;

    // ---- 31 Euler steps ----
    for (int s = 0; s < 31; ++s) {
        // L0: Yh -> buf8A (fp16 weights, reg pipeline)
        mlp0(Yh, buf8A, Wb0, b0v, w, l15, lhi, lane);
        stage2(wb1, ringW, 0);         // prefetch L1 chunks 0,1 (survives lightbar)
        lightbar();

        // L1: buf8A -> buf8B (int8, async ring)
        mlp8c(buf8A, buf8B, wb1, ringW, ringR, b1v, w, l15, lhi);
        stage2(wb2, ringW, 0);         // prefetch L2 chunks 0,1
        lightbar();

        // L2: buf8B -> buf8A
        mlp8c(buf8B, buf8A, wb2, ringW, ringR, b2v, w, l15, lhi);
        __syncthreads();

        // L3: DY[16][128] = buf8A @ W3q^T + b3 (int8, K split across wave halves)
        {
            i4 acc3; acc3[0]=0; acc3[1]=0; acc3[2]=0; acc3[3]=0;
            i4 c3E, c3O, x3E, x3O;
            auto loadB3 = [&](i4& b, int kk) {
                b = *(const i4*)(wb3 + (size_t)kk * 1024);
            };
            auto loadA3 = [&](i4& a, int kk) {
                int byte = (l15 * 1024 + kk * 64 + lhi * 16) ^ ((l15 & 7) << 4);
                a = *(const i4*)(buf8A + byte);
            };
            loadB3(c3E, kk0 + 0); loadA3(x3E, kk0 + 0);
#pragma unroll
            for (int p = 0; p < 3; ++p) {
                loadB3(c3O, kk0 + 2 * p + 1); loadA3(x3O, kk0 + 2 * p + 1);
                acc3 = __builtin_amdgcn_mfma_i32_16x16x64_i8(x3E, c3E, acc3, 0, 0, 0);
                loadB3(c3E, kk0 + 2 * p + 2); loadA3(x3E, kk0 + 2 * p + 2);
                acc3 = __builtin_amdgcn_mfma_i32_16x16x64_i8(x3O, c3O, acc3, 0, 0, 0);
            }
            loadB3(c3O, kk0 + 7); loadA3(x3O, kk0 + 7);
            acc3 = __builtin_amdgcn_mfma_i32_16x16x64_i8(x3E, c3E, acc3, 0, 0, 0);
            acc3 = __builtin_amdgcn_mfma_i32_16x16x64_i8(x3O, c3O, acc3, 0, 0, 0);

            if (w >= 8)
                red[cg * 64 + lane] = acc3;
            __syncthreads();
            if (w < 8) {
                i4 part = red[w * 64 + lane];
#pragma unroll
                for (int j = 0; j < 4; ++j) {
                    int row = lhi * 4 + j;
                    float dy = (float)(acc3[j] + part[j]) * DEQ3 + b3v;
                    float nv = yreg[j] + dtv * dy;
                    yreg[j] = nv;
                    int byte = ((row * 128 + g) * 2) ^ ((row & 7) << 4);
                    *(_Float16*)(Yh + byte) = (_Float16)nv;
                }
            }
        }
        __syncthreads();
    }

    // ---- output: out[token][0:64] from registers (cols 0..63 = waves 0..3) ----
    if (w < 4) {
#pragma unroll
        for (int j = 0; j < 4; ++j) {
            int row = lhi * 4 + j;
            out[(size_t)(row0 + row) * 64 + g] = yreg[j];
        }
    }
}

extern "C" void kernel_launch(void* const* d_in, const int* in_sizes, int n_in,
                              void* d_out, int out_size, void* d_ws, size_t ws_size,
                              hipStream_t stream)
{
    const float* y0    = (const float*)d_in[0];
    const float* tarr  = (const float*)d_in[1];
    const float* W_aug = (const float*)d_in[2];
    const float* b_aug = (const float*)d_in[3];
    const float* W0    = (const float*)d_in[4];
    const float* b0    = (const float*)d_in[5];
    const float* W1    = (const float*)d_in[6];
    const float* b1    = (const float*)d_in[7];
    const float* W2    = (const float*)d_in[8];
    const float* b2    = (const float*)d_in[9];
    const float* W3    = (const float*)d_in[10];
    const float* b3    = (const float*)d_in[11];

    // d_ws layout (bytes): W0p fp16 @0 (262144), W1q @262144 (1048576),
    //                      W2q @1310720 (1048576), W3q @2359296 (131072)
    _Float16* W0p = (_Float16*)d_ws;
    char* W1q = (char*)d_ws + 262144;
    char* W2q = (char*)d_ws + 1310720;
    char* W3q = (char*)d_ws + 2359296;

    pack_kernel<128><<<16384 / 256, 256, 0, stream>>>(W0, W0p, 16384);
    pack8_kernel<<<65536 / 256, 256, 0, stream>>>(W1, W1q, 65536);
    pack8_kernel<<<65536 / 256, 256, 0, stream>>>(W2, W2q, 65536);
    pack3q_kernel<<<8192 / 256, 256, 0, stream>>>(W3, W3q, 8192);

    node_kernel<<<NBLK, NTHREADS, 0, stream>>>(y0, tarr, W_aug, b_aug,
                                               b0, b1, b2, b3,
                                               W0p, W1q, W2q, W3q,
                                               (float*)d_out);
}

// Round 14
// 1239.987 us; speedup vs baseline: 1.8783x; 1.0334x over previous
//
#include <hip/hip_runtime.h>

typedef _Float16 h8 __attribute__((ext_vector_type(8)));
typedef float f32x4 __attribute__((ext_vector_type(4)));
typedef int  i4 __attribute__((ext_vector_type(4)));

#define NTHREADS 1024
#define ROWS 16
#define NBLK 256   // 4096 tokens / 16 rows

// LDS layout (bytes), total = 160 KiB:
//   buf8A : 16x1024 int8 swizzled @      0 (16384)
//   buf8B : 16x1024 int8 swizzled @  16384 (16384)
//           Yh fp16 16x128 swz    @  16384 ( 4096)  (alias; dead while buf8B live)
//           red i4[512]           @  24576 ( 8192)  (alias; L3 reduce)
//   ring  : 16 waves x 2 slots x 4096 @ 32768 (131072)  async W staging
#define SMEM_BYTES 163840

#define GLOAD16(gp, lp) __builtin_amdgcn_global_load_lds( \
    (const __attribute__((address_space(1))) void*)(gp),  \
    (__attribute__((address_space(3))) void*)(lp), 16, 0, 0)

__device__ __forceinline__ float fast_tanh(float x) {
    float e = __expf(2.0f * x);
    return 1.0f - 2.0f / (e + 1.0f);
}

// flush LDS + block barrier WITHOUT draining vmcnt (keeps async prefetch alive)
__device__ __forceinline__ void lightbar() {
    asm volatile("s_waitcnt lgkmcnt(0)" ::: "memory");
    __builtin_amdgcn_sched_barrier(0);
    __builtin_amdgcn_s_barrier();
    __builtin_amdgcn_sched_barrier(0);
}

// ---------------- weight pack kernels ----------------
template<int K>
__global__ void __launch_bounds__(256) pack_kernel(const float* __restrict__ src,
                                                   _Float16* __restrict__ dst, int nfrag) {
    constexpr int NK = K / 32;
    int idx = blockIdx.x * 256 + threadIdx.x;
    if (idx >= nfrag) return;
    int lane = idx & 63;
    int ct   = (idx >> 6) & 3;
    int kk   = (idx >> 8) % NK;
    int w    = idx / (256 * NK);
    int col  = w * 64 + ct * 16 + (lane & 15);
    int kb   = kk * 32 + (lane >> 4) * 8;
    const float* s = src + (size_t)col * K + kb;
    f32x4 v0 = *(const f32x4*)s;
    f32x4 v1 = *(const f32x4*)(s + 4);
    h8 h;
    h[0]=(_Float16)v0[0]; h[1]=(_Float16)v0[1]; h[2]=(_Float16)v0[2]; h[3]=(_Float16)v0[3];
    h[4]=(_Float16)v1[0]; h[5]=(_Float16)v1[1]; h[6]=(_Float16)v1[2]; h[7]=(_Float16)v1[3];
    *(h8*)(dst + (size_t)idx * 8) = h;
}

__global__ void __launch_bounds__(256) pack8_kernel(const float* __restrict__ src,
                                                    char* __restrict__ dst, int nfrag) {
    int idx = blockIdx.x * 256 + threadIdx.x;
    if (idx >= nfrag) return;
    int lane = idx & 63;
    int ct   = (idx >> 6) & 3;
    int kk   = (idx >> 8) & 15;
    int w    = idx >> 12;
    int col  = w * 64 + ct * 16 + (lane & 15);
    int kb   = kk * 64 + (lane >> 4) * 16;
    const float* s = src + (size_t)col * 1024 + kb;
    union { char q[16]; i4 v; } u;
#pragma unroll
    for (int j = 0; j < 16; ++j)
        u.q[j] = (char)__float2int_rn(s[j] * 4064.0f);   // 32*127
    *(i4*)(dst + (size_t)idx * 16) = u.v;
}

__global__ void __launch_bounds__(256) pack3q_kernel(const float* __restrict__ src,
                                                     char* __restrict__ dst, int nfrag) {
    int idx = blockIdx.x * 256 + threadIdx.x;
    if (idx >= nfrag) return;
    int lane = idx & 63;
    int kk   = (idx >> 6) & 15;
    int cg   = idx >> 10;
    int col  = cg * 16 + (lane & 15);
    int kb   = kk * 64 + (lane >> 4) * 16;
    const float* s = src + (size_t)col * 1024 + kb;
    union { char q[16]; i4 v; } u;
#pragma unroll
    for (int j = 0; j < 16; ++j)
        u.q[j] = (char)__float2int_rn(s[j] * 4064.0f);
    *(i4*)(dst + (size_t)idx * 16) = u.v;
}

// ---------------- layer 0: fp16 x fp16 (K=128), reg ping-pong ----------------
__device__ __forceinline__ void mlp0(const char* __restrict__ src, char* __restrict__ dst,
                                     const _Float16* __restrict__ Wp, f32x4 bv,
                                     int w, int l15, int lhi, int lane)
{
    constexpr int NK = 4;
    const int colbase = w * 64;
    const _Float16* wb = Wp + (size_t)w * NK * 2048 + lane * 8;

    f32x4 acc[4];
#pragma unroll
    for (int ct = 0; ct < 4; ++ct) {
        f32x4 a; a[0] = bv[ct]; a[1] = bv[ct]; a[2] = bv[ct]; a[3] = bv[ct];
        acc[ct] = a;
    }

    h8 bE[4], bO[4], aE, aO;
    auto loadB = [&](h8* b, int kk) {
#pragma unroll
        for (int ct = 0; ct < 4; ++ct)
            b[ct] = *(const h8*)(wb + (size_t)kk * 2048 + ct * 512);
    };
    auto loadA = [&](h8& a, int kk) {
        int byte = (l15 * 256 + kk * 64 + lhi * 16) ^ ((l15 & 7) << 4);
        a = *(const h8*)(src + byte);
    };
    auto mfma4 = [&](h8& a, h8* b) {
        __builtin_amdgcn_s_setprio(1);
#pragma unroll
        for (int ct = 0; ct < 4; ++ct)
            acc[ct] = __builtin_amdgcn_mfma_f32_16x16x32_f16(a, b[ct], acc[ct], 0, 0, 0);
        __builtin_amdgcn_s_setprio(0);
    };

    loadB(bE, 0); loadA(aE, 0);
    loadB(bO, 1); loadA(aO, 1);
    mfma4(aE, bE);
    loadB(bE, 2); loadA(aE, 2);
    mfma4(aO, bO);
    loadB(bO, 3); loadA(aO, 3);
    mfma4(aE, bE);
    mfma4(aO, bO);

#pragma unroll
    for (int ct = 0; ct < 4; ++ct)
#pragma unroll
        for (int j = 0; j < 4; ++j) {
            int row = lhi * 4 + j;
            int gc = colbase + ct * 16 + l15;
            int q = __float2int_rn(fast_tanh(acc[ct][j]) * 127.0f);
            int byte = (row * 1024 + gc) ^ ((row & 7) << 4);
            *(char*)(dst + byte) = (char)q;
        }
}

// ---- async staging: issue chunks 0,1 (4 x 16B gload_lds each) into wave ring ----
__device__ __forceinline__ void stage2(const char* wbl, char* ringW)
{
#pragma unroll
    for (int c = 0; c < 2; ++c) {
        const char* g = wbl + (size_t)c * 4096;
        char* l = ringW + c * 4096;
#pragma unroll
        for (int ct = 0; ct < 4; ++ct)
            GLOAD16(g + ct * 1024, l + ct * 1024);
    }
}

// ------- layers 1/2: int8, B via vmcnt-counted LDS ring; tail-issues next stage -------
__device__ __forceinline__ void mlp8c(const char* __restrict__ src, char* __restrict__ dst,
                                      const char* wbl, char* ringW, const char* ringR,
                                      f32x4 bv, int w, int l15, int lhi,
                                      const char* nextwb)
{
    const int colbase = w * 64;
    i4 acc[4];
#pragma unroll
    for (int ct = 0; ct < 4; ++ct) { i4 z; z[0]=0; z[1]=0; z[2]=0; z[3]=0; acc[ct] = z; }

    i4 B0, B1, B2, B3, A;
    auto readSlot = [&](int kk) {
        const char* sl = ringR + (kk & 1) * 4096;
        B0 = *(const i4*)(sl);
        B1 = *(const i4*)(sl + 1024);
        B2 = *(const i4*)(sl + 2048);
        B3 = *(const i4*)(sl + 3072);
        int byte = (l15 * 1024 + kk * 64 + lhi * 16) ^ ((l15 & 7) << 4);
        A = *(const i4*)(src + byte);
    };
    auto mfma4 = [&]() {
        __builtin_amdgcn_s_setprio(1);
        acc[0] = __builtin_amdgcn_mfma_i32_16x16x64_i8(A, B0, acc[0], 0, 0, 0);
        acc[1] = __builtin_amdgcn_mfma_i32_16x16x64_i8(A, B1, acc[1], 0, 0, 0);
        acc[2] = __builtin_amdgcn_mfma_i32_16x16x64_i8(A, B2, acc[2], 0, 0, 0);
        acc[3] = __builtin_amdgcn_mfma_i32_16x16x64_i8(A, B3, acc[3], 0, 0, 0);
        __builtin_amdgcn_s_setprio(0);
    };

    // entry state: chunks 0,1 already issued earlier (may have landed — waits are conservative)
#pragma unroll 1
    for (int kk = 0; kk < 15; ++kk) {
        asm volatile("s_waitcnt vmcnt(4)" ::: "memory");   // chunk kk landed
        __builtin_amdgcn_sched_barrier(0);
        readSlot(kk);
        asm volatile("s_waitcnt lgkmcnt(0)" ::: "memory"); // slot reads done before reuse
        __builtin_amdgcn_sched_barrier(0);
        if (kk < 14) {                                     // issue chunk kk+2 into slot kk&1
            const char* g = wbl + (size_t)(kk + 2) * 4096;
            char* l = ringW + (kk & 1) * 4096;
#pragma unroll
            for (int ct = 0; ct < 4; ++ct)
                GLOAD16(g + ct * 1024, l + ct * 1024);
        }
        __builtin_amdgcn_sched_barrier(0);
        mfma4();
    }
    asm volatile("s_waitcnt vmcnt(0)" ::: "memory");       // chunk 15 landed
    __builtin_amdgcn_sched_barrier(0);
    readSlot(15);
    asm volatile("s_waitcnt lgkmcnt(0)" ::: "memory");
    __builtin_amdgcn_sched_barrier(0);
    // ring fully drained: tail-issue next stage's chunks 0,1 (hides under epilogue+barrier+next phase)
    stage2(nextwb, ringW);
    __builtin_amdgcn_sched_barrier(0);
    mfma4();

    const float DEQ = 1.0f / 516128.0f;   // 1/(32*127*127)
#pragma unroll
    for (int ct = 0; ct < 4; ++ct) {
        int gc = colbase + ct * 16 + l15;
#pragma unroll
        for (int j = 0; j < 4; ++j) {
            int row = lhi * 4 + j;
            float v = fast_tanh((float)acc[ct][j] * DEQ + bv[ct]);
            int q = __float2int_rn(v * 127.0f);
            int byte = (row * 1024 + gc) ^ ((row & 7) << 4);
            *(char*)(dst + byte) = (char)q;
        }
    }
}

__global__ void
__attribute__((amdgpu_flat_work_group_size(NTHREADS, NTHREADS)))
node_kernel(const float* __restrict__ y0,
            const float* __restrict__ tarr,
            const float* __restrict__ W_aug,
            const float* __restrict__ b_aug,
            const float* __restrict__ b0,
            const float* __restrict__ b1,
            const float* __restrict__ b2,
            const float* __restrict__ b3,
            const _Float16* __restrict__ W0p,
            const char* __restrict__ W1q,
            const char* __restrict__ W2q,
            const char* __restrict__ W3q,
            float* __restrict__ out)
{
    __shared__ __align__(16) char smem[SMEM_BYTES];
    char* buf8A = smem;
    char* buf8B = smem + 16384;
    char* Yh    = smem + 16384;            // alias buf8B[0:4096]
    i4*   red   = (i4*)(smem + 24576);     // alias buf8B[8192:16384]
    float* Yf   = (float*)smem;            // alias buf8A (init only)
    char* ring  = smem + 32768;

    const int tid  = threadIdx.x;
    const int lane = tid & 63;
    const int w    = tid >> 6;       // 0..15
    const int l15  = lane & 15;
    const int lhi  = lane >> 4;
    const int row0 = blockIdx.x * ROWS;

    const float dtv = tarr[1] - tarr[0];

    // ---- load y0 rows into Yf[:, 0:64] ----
    if (tid < 256) {
        int idx = tid * 4;
        int r = idx >> 6;
        int c = idx & 63;
        f32x4 v = *(const f32x4*)(y0 + (size_t)(row0 + r) * 64 + c);
        *(f32x4*)(Yf + r * 128 + c) = v;
    }
    __syncthreads();

    // ---- augment ----
    {
        int r = tid >> 6;
        int a0 = tid & 63;
        float acc = b_aug[a0];
        for (int d = 0; d < 64; ++d)
            acc += Yf[r * 128 + d] * W_aug[a0 * 64 + d];
        __syncthreads();
        Yf[r * 128 + 64 + a0] = acc;
    }
    __syncthreads();

    // thread-owned state (waves 0..7): col g = w*16+l15, rows lhi*4+j
    const int g = w * 16 + l15;
    f32x4 yreg;
    if (w < 8) {
#pragma unroll
        for (int j = 0; j < 4; ++j)
            yreg[j] = Yf[(lhi * 4 + j) * 128 + g];
    }
    h8 yh0;
    int yh0_byte;
    if (tid < 256) {
        int r = tid >> 4;
        int c = (tid & 15) * 8;
        const float* p = Yf + r * 128 + c;
#pragma unroll
        for (int j = 0; j < 8; ++j) yh0[j] = (_Float16)p[j];
        yh0_byte = ((r * 128 + c) * 2) ^ ((r & 7) << 4);
    }
    __syncthreads();
    if (tid < 256) *(h8*)(Yh + yh0_byte) = yh0;
    __syncthreads();

    // per-wave pointers
    const char* wb1 = W1q + (size_t)w * 65536 + lane * 16;
    const char* wb2 = W2q + (size_t)w * 65536 + lane * 16;
    char* ringW = ring + w * 8192;           // wave-uniform slot base
    const char* ringR = ringW + lane * 16;   // per-lane read base

    // biases in registers (keep vmcnt clean inside mlp8c)
    f32x4 b0v, b1v, b2v;
#pragma unroll
    for (int ct = 0; ct < 4; ++ct) {
        b0v[ct] = b0[w * 64 + ct * 16 + l15];
        b1v[ct] = b1[w * 64 + ct * 16 + l15];
        b2v[ct] = b2[w * 64 + ct * 16 + l15];
    }
    const int cg  = w & 7;
    const int kk0 = (w >> 3) * 8;
    const char* wb3 = W3q + (size_t)cg * 16384 + lane * 16;
    const float b3v = (w < 8) ? b3[g] : 0.0f;
    const float DEQ3 = 1.0f / 516128.0f;

    // prologue: stage L1 chunks 0,1 for step 0
    stage2(wb1, ringW);

    // ---- 31 Euler steps ----
    for (int s = 0; s < 31; ++s) {
        // L0: Yh -> buf8A (L1 chunks already in flight/landed)
        mlp0(Yh, buf8A, W0p, b0v, w, l15, lhi, lane);
        lightbar();

        // L1: buf8A -> buf8B; tail-issues L2 chunks 0,1
        mlp8c(buf8A, buf8B, wb1, ringW, ringR, b1v, w, l15, lhi, wb2);
        lightbar();

        // L2: buf8B -> buf8A; tail-issues NEXT STEP's L1 chunks 0,1
        mlp8c(buf8B, buf8A, wb2, ringW, ringR, b2v, w, l15, lhi, wb1);
        lightbar();

        // L3: DY[16][128] = buf8A @ W3q^T + b3 (int8, K split across wave halves)
        {
            i4 acc3; acc3[0]=0; acc3[1]=0; acc3[2]=0; acc3[3]=0;
            i4 c3E, c3O, x3E, x3O;
            auto loadB3 = [&](i4& b, int kk) {
                b = *(const i4*)(wb3 + (size_t)kk * 1024);
            };
            auto loadA3 = [&](i4& a, int kk) {
                int byte = (l15 * 1024 + kk * 64 + lhi * 16) ^ ((l15 & 7) << 4);
                a = *(const i4*)(buf8A + byte);
            };
            loadB3(c3E, kk0 + 0); loadA3(x3E, kk0 + 0);
#pragma unroll
            for (int q = 0; q < 3; ++q) {
                loadB3(c3O, kk0 + 2 * q + 1); loadA3(x3O, kk0 + 2 * q + 1);
                acc3 = __builtin_amdgcn_mfma_i32_16x16x64_i8(x3E, c3E, acc3, 0, 0, 0);
                loadB3(c3E, kk0 + 2 * q + 2); loadA3(x3E, kk0 + 2 * q + 2);
                acc3 = __builtin_amdgcn_mfma_i32_16x16x64_i8(x3O, c3O, acc3, 0, 0, 0);
            }
            loadB3(c3O, kk0 + 7); loadA3(x3O, kk0 + 7);
            acc3 = __builtin_amdgcn_mfma_i32_16x16x64_i8(x3E, c3E, acc3, 0, 0, 0);
            acc3 = __builtin_amdgcn_mfma_i32_16x16x64_i8(x3O, c3O, acc3, 0, 0, 0);

            if (w >= 8)
                red[cg * 64 + lane] = acc3;
            lightbar();
            if (w < 8) {
                i4 part = red[w * 64 + lane];
#pragma unroll
                for (int j = 0; j < 4; ++j) {
                    int row = lhi * 4 + j;
                    float dy = (float)(acc3[j] + part[j]) * DEQ3 + b3v;
                    float nv = yreg[j] + dtv * dy;
                    yreg[j] = nv;
                    int byte = ((row * 128 + g) * 2) ^ ((row & 7) << 4);
                    *(_Float16*)(Yh + byte) = (_Float16)nv;
                }
            }
        }
        lightbar();
    }

    // drain dangling prefetch (last step tail-issued L1 chunks we never consume)
    asm volatile("s_waitcnt vmcnt(0)" ::: "memory");

    // ---- output ----
    if (w < 4) {
#pragma unroll
        for (int j = 0; j < 4; ++j) {
            int row = lhi * 4 + j;
            out[(size_t)(row0 + row) * 64 + g] = yreg[j];
        }
    }
}

extern "C" void kernel_launch(void* const* d_in, const int* in_sizes, int n_in,
                              void* d_out, int out_size, void* d_ws, size_t ws_size,
                              hipStream_t stream)
{
    const float* y0    = (const float*)d_in[0];
    const float* tarr  = (const float*)d_in[1];
    const float* W_aug = (const float*)d_in[2];
    const float* b_aug = (const float*)d_in[3];
    const float* W0    = (const float*)d_in[4];
    const float* b0    = (const float*)d_in[5];
    const float* W1    = (const float*)d_in[6];
    const float* b1    = (const float*)d_in[7];
    const float* W2    = (const float*)d_in[8];
    const float* b2    = (const float*)d_in[9];
    const float* W3    = (const float*)d_in[10];
    const float* b3    = (const float*)d_in[11];

    _Float16* W0p = (_Float16*)d_ws;
    char* W1q = (char*)d_ws + 262144;
    char* W2q = (char*)d_ws + 1310720;
    char* W3q = (char*)d_ws + 2359296;

    pack_kernel<128><<<16384 / 256, 256, 0, stream>>>(W0, W0p, 16384);
    pack8_kernel<<<65536 / 256, 256, 0, stream>>>(W1, W1q, 65536);
    pack8_kernel<<<65536 / 256, 256, 0, stream>>>(W2, W2q, 65536);
    pack3q_kernel<<<8192 / 256, 256, 0, stream>>>(W3, W3q, 8192);

    node_kernel<<<NBLK, NTHREADS, 0, stream>>>(y0, tarr, W_aug, b_aug,
                                               b0, b1, b2, b3,
                                               W0p, W1q, W2q, W3q,
                                               (float*)d_out);
}